// Round 3
// baseline (994.106 us; speedup 1.0000x reference)
//
#include <hip/hip_runtime.h>
#include <math.h>

#define NN 768
#define KALL 1152     // 192*3 + 144*2 + 288
#define CATD 2112     // 192 + 3*96 + 96 + 1536
#define INF_ 100000.0f

__device__ __forceinline__ float4 ld4(const float* p) { return *(const float4*)p; }

// ---------------- 1. pack combined projection weights (q scaled by 0.25) ----------------
__global__ __launch_bounds__(256) void pack_kernel(
    const float* wq, const float* bq, const float* wk, const float* bk,
    const float* wv, const float* bv, const float* wqp, const float* bqp,
    const float* wkp, const float* bkp, const float* wvp, const float* bvp,
    float* Wall, float* ball) {
  int idx = blockIdx.x * 256 + threadIdx.x;
  if (idx >= 385 * KALL) return;
  int kk = idx / KALL, u = idx - kk * KALL;
  const float *w, *b; int col, dim; float sc = 1.f;
  if (u < 192)      { w = wq;  b = bq;  col = u;       dim = 192; sc = 0.25f; }
  else if (u < 384) { w = wk;  b = bk;  col = u - 192; dim = 192; }
  else if (u < 576) { w = wv;  b = bv;  col = u - 384; dim = 192; }
  else if (u < 720) { w = wqp; b = bqp; col = u - 576; dim = 144; }
  else if (u < 864) { w = wkp; b = bkp; col = u - 720; dim = 144; }
  else              { w = wvp; b = bvp; col = u - 864; dim = 288; }
  if (kk < 384) Wall[kk * KALL + u] = sc * w[kk * dim + col];
  else          ball[u] = sc * b[col];
}

// ---------------- 2. proj = s @ Wall + ball   [768 x 1152] ----------------
__global__ __launch_bounds__(256) void proj_kernel(const float* s, const float* Wall,
                                                   const float* ball, float* proj) {
  int q0 = blockIdx.x * 32, c0 = blockIdx.y * 64;
  int tid = threadIdx.x;
  int qa = q0 + (tid >> 4) * 2, qb = qa + 1;
  int c = c0 + (tid & 15) * 4;
  const float* sa = s + qa * 384;
  const float* sb = s + qb * 384;
  const float* wp = Wall + c;
  float4 acc0 = {0, 0, 0, 0}, acc1 = {0, 0, 0, 0};
#pragma unroll 4
  for (int k = 0; k < 384; k++) {
    float4 w4 = ld4(wp + k * KALL);
    float a0 = sa[k], a1 = sb[k];
    acc0.x += a0 * w4.x; acc0.y += a0 * w4.y; acc0.z += a0 * w4.z; acc0.w += a0 * w4.w;
    acc1.x += a1 * w4.x; acc1.y += a1 * w4.y; acc1.z += a1 * w4.z; acc1.w += a1 * w4.w;
  }
  float4 b4 = ld4(ball + c);
  acc0.x += b4.x; acc0.y += b4.y; acc0.z += b4.z; acc0.w += b4.w;
  acc1.x += b4.x; acc1.y += b4.y; acc1.z += b4.z; acc1.w += b4.w;
  *(float4*)(proj + (size_t)qa * KALL + c) = acc0;
  *(float4*)(proj + (size_t)qb * KALL + c) = acc1;
}

// ---------------- 3. rigid-transform points + q2/k2 ----------------
__global__ __launch_bounds__(256) void points_kernel(const float* proj, const float* rot,
                                                     const float* trans, float* qpts, float* kpts,
                                                     float* vpts, float* q2, float* k2) {
  int n = blockIdx.x, tid = threadIdx.x;
  __shared__ float sq[12], sk[12];
  if (tid < 12) { sq[tid] = 0.f; sk[tid] = 0.f; }
  __syncthreads();
  if (tid < 192) {
    const float* R = rot + n * 9;
    const float* T = trans + n * 3;
    const float* pr = proj + (size_t)n * KALL;
    int base, P; float* outp; int h; bool isq = false, isk = false;
    if (tid < 48)      { h = tid >> 2; int p = tid & 3; base = 576 + h * 12; P = 4;
                         outp = qpts + n * 144 + h * 12 + p * 3; base += p; isq = true; }
    else if (tid < 96) { int i = tid - 48; h = i >> 2; int p = i & 3; base = 720 + h * 12; P = 4;
                         outp = kpts + n * 144 + h * 12 + p * 3; base += p; isk = true; }
    else               { int i = tid - 96; h = i >> 3; int p = i & 7; base = 864 + h * 24; P = 8;
                         outp = vpts + n * 288 + h * 24 + p * 3; base += p; }
    float l0 = pr[base], l1 = pr[base + P], l2 = pr[base + 2 * P];
    float g0 = R[0] * l0 + R[1] * l1 + R[2] * l2 + T[0];
    float g1 = R[3] * l0 + R[4] * l1 + R[5] * l2 + T[1];
    float g2 = R[6] * l0 + R[7] * l1 + R[8] * l2 + T[2];
    outp[0] = g0; outp[1] = g1; outp[2] = g2;
    float ns = g0 * g0 + g1 * g1 + g2 * g2;
    if (isq) atomicAdd(&sq[h], ns);
    else if (isk) atomicAdd(&sk[h], ns);
  }
  __syncthreads();
  if (tid < 12) { q2[n * 12 + tid] = sq[tid]; k2[n * 12 + tid] = sk[tid]; }
}

// ---------------- 4. fused bias + logits + softmax: one block per q ----------------
// Phase 1 (tid<192): thread owns 4 strided k-rows (k = t, t+192, t+384, t+576), all 12 h.
//   z streamed from global as float4 (registers); wb broadcast from LDS as float4,
//   amortized over 4 k-rows -> 16 FMA per LDS instr. Then adds qk / point / mask terms.
// Phase 2: wave w softmaxes 3 heads over k=768 via butterfly shuffles; writes final a.
__global__ __launch_bounds__(256) void attn_kernel(
    const float* z, const float* wb, const float* bb, const float* proj,
    const float* qpts, const float* kpts, const float* q2, const float* k2,
    const float* mask, const float* hw, float* abuf) {
  int q = blockIdx.x;
  int tid = threadIdx.x;
  __shared__ float wbt[12][132];   // wb transposed [h][c]
  __shared__ float qws[192], qps[144];
  __shared__ float q2s_[12], bbs_[12], pws_[12];
  __shared__ float mq_s;
  __shared__ float a_lds[768 * 13];  // logits [k][h], stride 13 (conflict-free)

  for (int i = tid; i < 1536; i += 256) { int h = i >> 7, c = i & 127; wbt[h][c] = wb[c * 12 + h]; }
  if (tid < 192) qws[tid] = proj[(size_t)q * KALL + tid];
  if (tid < 144) qps[tid] = qpts[q * 144 + tid];
  if (tid < 12) {
    q2s_[tid] = q2[q * 12 + tid];
    bbs_[tid] = bb[tid];
    float x = hw[tid];
    pws_[tid] = 0.23570226039551584f * (fmaxf(x, 0.f) + log1pf(__expf(-fabsf(x))));
  }
  if (tid == 12) mq_s = mask[q];
  __syncthreads();

  if (tid < 192) {
    int t = tid;
    float acc[12][4];
#pragma unroll
    for (int h = 0; h < 12; h++)
#pragma unroll
      for (int r = 0; r < 4; r++) acc[h][r] = 0.f;
    const float* zr = z + ((size_t)q * NN + t) * 128;
    for (int c4 = 0; c4 < 128; c4 += 4) {
      float4 zv[4];
      zv[0] = ld4(zr + c4);
      zv[1] = ld4(zr + 192 * 128 + c4);
      zv[2] = ld4(zr + 384 * 128 + c4);
      zv[3] = ld4(zr + 576 * 128 + c4);
#pragma unroll
      for (int h = 0; h < 12; h++) {
        float4 w4 = ld4(&wbt[h][c4]);
#pragma unroll
        for (int r = 0; r < 4; r++) {
          acc[h][r] += zv[r].x * w4.x + zv[r].y * w4.y + zv[r].z * w4.z + zv[r].w * w4.w;
        }
      }
    }
    float mq = mq_s;
    float mterm[4];
#pragma unroll
    for (int r = 0; r < 4; r++) mterm[r] = INF_ * (mq * mask[t + 192 * r] - 1.f);
    for (int h = 0; h < 12; h++) {
      float qwh[16], qph[12];
#pragma unroll
      for (int j = 0; j < 16; j++) qwh[j] = qws[h * 16 + j];
#pragma unroll
      for (int j = 0; j < 12; j++) qph[j] = qps[h * 12 + j];
      float q2v = q2s_[h], pwv = pws_[h], bbv = bbs_[h];
#pragma unroll
      for (int r = 0; r < 4; r++) {
        int k = t + 192 * r;
        const float* kwp = proj + (size_t)k * KALL + 192 + h * 16;
        float4 a0 = ld4(kwp), a1 = ld4(kwp + 4), a2 = ld4(kwp + 8), a3 = ld4(kwp + 12);
        float dqk = a0.x * qwh[0] + a0.y * qwh[1] + a0.z * qwh[2] + a0.w * qwh[3]
                  + a1.x * qwh[4] + a1.y * qwh[5] + a1.z * qwh[6] + a1.w * qwh[7]
                  + a2.x * qwh[8] + a2.y * qwh[9] + a2.z * qwh[10] + a2.w * qwh[11]
                  + a3.x * qwh[12] + a3.y * qwh[13] + a3.z * qwh[14] + a3.w * qwh[15];
        const float* kpp = kpts + (size_t)k * 144 + h * 12;
        float4 p0 = ld4(kpp), p1 = ld4(kpp + 4), p2 = ld4(kpp + 8);
        float dpt = p0.x * qph[0] + p0.y * qph[1] + p0.z * qph[2] + p0.w * qph[3]
                  + p1.x * qph[4] + p1.y * qph[5] + p1.z * qph[6] + p1.w * qph[7]
                  + p2.x * qph[8] + p2.y * qph[9] + p2.z * qph[10] + p2.w * qph[11];
        float k2v = k2[k * 12 + h];
        float L = (acc[h][r] + bbv + dqk - 0.5f * pwv * (q2v + k2v - 2.f * dpt) + mterm[r])
                  * 0.5773502691896258f;
        a_lds[k * 13 + h] = L;
      }
    }
  }
  __syncthreads();

  // softmax: wave w handles h = w, w+4, w+8
  int w = tid >> 6, lane = tid & 63;
#pragma unroll
  for (int hh = 0; hh < 3; hh++) {
    int h = w + 4 * hh;
    float v[12];
    float mx = -1e30f;
#pragma unroll
    for (int i = 0; i < 12; i++) {
      v[i] = a_lds[(lane + 64 * i) * 13 + h];
      mx = fmaxf(mx, v[i]);
    }
#pragma unroll
    for (int d = 1; d < 64; d <<= 1) mx = fmaxf(mx, __shfl_xor(mx, d, 64));
    float s = 0.f;
#pragma unroll
    for (int i = 0; i < 12; i++) { v[i] = __expf(v[i] - mx); s += v[i]; }
#pragma unroll
    for (int d = 1; d < 64; d <<= 1) s += __shfl_xor(s, d, 64);
    float inv = 1.f / s;
    float* ap = abuf + ((size_t)q * 12 + h) * NN + lane;
#pragma unroll
    for (int i = 0; i < 12; i++) ap[64 * i] = v[i] * inv;
  }
}

// ---------------- 5. o_pair[q][h][c] = sum_k a[q,h,k] z[q,k,c]  -> cat cols 576.. ----------------
// one block per q; a staged in LDS ([h][k], broadcast float4 reads); 12 heads/thread; k split 2-way
__global__ __launch_bounds__(256) void opair_kernel(const float* z, const float* abuf, float* cat) {
  int q = blockIdx.x, tid = threadIdx.x;
  __shared__ float a_s[9216];    // [h][k]
  __shared__ float red[1536];    // [h][c] partial from half 1
  for (int i = tid; i < 9216; i += 256) a_s[i] = abuf[(size_t)q * 9216 + i];
  __syncthreads();
  int c = tid & 127, half = tid >> 7;
  const float* zc = z + ((size_t)q * NN + half * 384) * 128 + c;
  float acc[12] = {0, 0, 0, 0, 0, 0, 0, 0, 0, 0, 0, 0};
  for (int k4 = 0; k4 < 384; k4 += 4) {
    float z0 = zc[(size_t)(k4 + 0) * 128];
    float z1 = zc[(size_t)(k4 + 1) * 128];
    float z2 = zc[(size_t)(k4 + 2) * 128];
    float z3 = zc[(size_t)(k4 + 3) * 128];
    int kb = half * 384 + k4;
#pragma unroll
    for (int h = 0; h < 12; h++) {
      float4 a4 = *(const float4*)&a_s[h * NN + kb];
      acc[h] += a4.x * z0 + a4.y * z1 + a4.z * z2 + a4.w * z3;
    }
  }
  if (half == 1) {
#pragma unroll
    for (int h = 0; h < 12; h++) red[h * 128 + c] = acc[h];
  }
  __syncthreads();
  if (half == 0) {
#pragma unroll
    for (int h = 0; h < 12; h++)
      cat[(size_t)q * CATD + 576 + h * 128 + c] = acc[h] + red[h * 128 + c];
  }
}

// ---------------- 6. o + o_pt (inverse rigid + norm) -> cat cols 0..576 ----------------
// grid (12, 32): head h, 24 q per block; active thread t<240: q=t/10, g=t%10 (10 float4 groups)
__global__ __launch_bounds__(256) void ov_kernel(const float* proj, const float* vpts,
                                                 const float* abuf, const float* rot,
                                                 const float* trans, float* cat) {
  int h = blockIdx.x, q0 = blockIdx.y * 24;
  int tid = threadIdx.x;
  __shared__ float opt[24][24];
  if (tid < 240) {
    int ql = tid / 10, g = tid - ql * 10;
    int q = q0 + ql;
    const float* ap = abuf + ((size_t)q * 12 + h) * NN;
    const float* vb;
    int stride;
    if (g < 4) { vb = proj + 384 + h * 16 + g * 4; stride = KALL; }
    else       { vb = vpts + h * 24 + (g - 4) * 4; stride = 288;  }
    float4 acc = {0, 0, 0, 0};
#pragma unroll 4
    for (int k = 0; k < NN; k++) {
      float av = ap[k];
      float4 v4 = ld4(vb + (size_t)k * stride);
      acc.x += av * v4.x; acc.y += av * v4.y; acc.z += av * v4.z; acc.w += av * v4.w;
    }
    if (g < 4) {
      *(float4*)(cat + (size_t)q * CATD + h * 16 + g * 4) = acc;
    } else {
      *(float4*)(&opt[ql][(g - 4) * 4]) = acc;
    }
  }
  __syncthreads();
  if (tid < 192) {
    int ql = tid >> 3, p = tid & 7;
    int q = q0 + ql;
    float gx = opt[ql][p * 3], gy = opt[ql][p * 3 + 1], gz = opt[ql][p * 3 + 2];
    const float* R = rot + q * 9;
    const float* T = trans + q * 3;
    float dx = gx - T[0], dy = gy - T[1], dz = gz - T[2];
    float lx = R[0] * dx + R[3] * dy + R[6] * dz;  // R^T
    float ly = R[1] * dx + R[4] * dy + R[7] * dz;
    float lz = R[2] * dx + R[5] * dy + R[8] * dz;
    float nrm = sqrtf(lx * lx + ly * ly + lz * lz + 1e-8f);
    int hp = h * 8 + p;
    float* co = cat + (size_t)q * CATD;
    co[192 + hp] = lx; co[288 + hp] = ly; co[384 + hp] = lz; co[480 + hp] = nrm;
  }
}

// ---------------- 7a. out partials: split-K GEMM  cat[768x2112] @ wo[2112x384] ----------------
__global__ __launch_bounds__(256) void out_part_kernel(const float* cat, const float* wo,
                                                       float* part) {
  int q0 = blockIdx.x * 16, c0 = blockIdx.y * 64, k0 = blockIdx.z * 264;
  int tid = threadIdx.x;
  int q = q0 + (tid >> 4);
  int c = c0 + (tid & 15) * 4;
  const float* cp = cat + (size_t)q * CATD + k0;
  const float* wp = wo + (size_t)k0 * 384 + c;
  float4 acc = {0, 0, 0, 0};
#pragma unroll 8
  for (int k = 0; k < 264; k++) {
    float a = cp[k];
    float4 w4 = ld4(wp + (size_t)k * 384);
    acc.x += a * w4.x; acc.y += a * w4.y; acc.z += a * w4.z; acc.w += a * w4.w;
  }
  *(float4*)(part + ((size_t)blockIdx.z * 768 + q) * 384 + c) = acc;
}

// ---------------- 7b. out = sum_j part[j] + b_o ----------------
__global__ __launch_bounds__(256) void out_reduce_kernel(const float* part, const float* bo,
                                                         float* out) {
  int idx = blockIdx.x * 256 + threadIdx.x;
  int q = idx / 96, cg = idx - q * 96;
  int c = cg * 4;
  float4 acc = ld4(bo + c);
#pragma unroll
  for (int j = 0; j < 8; j++) {
    float4 p = ld4(part + ((size_t)j * 768 + q) * 384 + c);
    acc.x += p.x; acc.y += p.y; acc.z += p.z; acc.w += p.w;
  }
  *(float4*)(out + (size_t)q * 384 + c) = acc;
}

extern "C" void kernel_launch(void* const* d_in, const int* in_sizes, int n_in,
                              void* d_out, int out_size, void* d_ws, size_t ws_size,
                              hipStream_t stream) {
  const float* s     = (const float*)d_in[0];
  const float* z     = (const float*)d_in[1];
  const float* rot   = (const float*)d_in[2];
  const float* trans = (const float*)d_in[3];
  const float* mask  = (const float*)d_in[4];
  const float* wq    = (const float*)d_in[5];
  const float* bq    = (const float*)d_in[6];
  const float* wk    = (const float*)d_in[7];
  const float* bk    = (const float*)d_in[8];
  const float* wv    = (const float*)d_in[9];
  const float* bv    = (const float*)d_in[10];
  const float* wqp   = (const float*)d_in[11];
  const float* bqp   = (const float*)d_in[12];
  const float* wkp   = (const float*)d_in[13];
  const float* bkp   = (const float*)d_in[14];
  const float* wvp   = (const float*)d_in[15];
  const float* bvp   = (const float*)d_in[16];
  const float* wb    = (const float*)d_in[17];
  const float* bb    = (const float*)d_in[18];
  const float* hw    = (const float*)d_in[19];
  const float* wo    = (const float*)d_in[20];
  const float* bo    = (const float*)d_in[21];
  float* out = (float*)d_out;

  float* ws = (float*)d_ws;
  float* proj  = ws;                       // 768*1152
  float* Wall  = proj + 884736;            // 384*1152
  float* ball  = Wall + 442368;            // 1152
  float* qpts  = ball + 1152;              // 768*144
  float* kpts  = qpts + 110592;            // 768*144
  float* vpts  = kpts + 110592;            // 768*288
  float* q2    = vpts + 221184;            // 768*12
  float* k2    = q2 + 9216;                // 768*12
  float* abuf  = k2 + 9216;                // 768*12*768
  float* cat   = abuf + 7077888;           // 768*2112
  float* part  = cat + 1622016;            // 8*768*384

  pack_kernel<<<dim3((385 * KALL + 255) / 256), 256, 0, stream>>>(
      wq, bq, wk, bk, wv, bv, wqp, bqp, wkp, bkp, wvp, bvp, Wall, ball);
  proj_kernel<<<dim3(24, 18), 256, 0, stream>>>(s, Wall, ball, proj);
  points_kernel<<<dim3(768), 256, 0, stream>>>(proj, rot, trans, qpts, kpts, vpts, q2, k2);
  attn_kernel<<<dim3(768), 256, 0, stream>>>(z, wb, bb, proj, qpts, kpts, q2, k2, mask, hw, abuf);
  opair_kernel<<<dim3(768), 256, 0, stream>>>(z, abuf, cat);
  ov_kernel<<<dim3(12, 32), 256, 0, stream>>>(proj, vpts, abuf, rot, trans, cat);
  out_part_kernel<<<dim3(48, 6, 8), 256, 0, stream>>>(cat, wo, part);
  out_reduce_kernel<<<dim3(288), 256, 0, stream>>>(part, bo, out);
}

// Round 4
// 981.882 us; speedup vs baseline: 1.0125x; 1.0125x over previous
//
#include <hip/hip_runtime.h>
#include <math.h>

#define NN 768
#define KALL 1152     // 192*3 + 144*2 + 288
#define CATD 2112     // 192 + 3*96 + 96 + 1536
#define INF_ 100000.0f

__device__ __forceinline__ float4 ld4(const float* p) { return *(const float4*)p; }

// ---------------- 1. pack combined projection weights (q scaled by 0.25) + wbt ----------------
__global__ __launch_bounds__(256) void pack_kernel(
    const float* wq, const float* bq, const float* wk, const float* bk,
    const float* wv, const float* bv, const float* wqp, const float* bqp,
    const float* wkp, const float* bkp, const float* wvp, const float* bvp,
    const float* wb, float* Wall, float* ball, float* wbt) {
  int idx = blockIdx.x * 256 + threadIdx.x;
  if (idx < 1536) {  // wbt[h][c] = wb[c][h]
    int h = idx % 12, c = idx / 12;
    wbt[h * 128 + c] = wb[c * 12 + h];
  }
  if (idx >= 385 * KALL) return;
  int kk = idx / KALL, u = idx - kk * KALL;
  const float *w, *b; int col, dim; float sc = 1.f;
  if (u < 192)      { w = wq;  b = bq;  col = u;       dim = 192; sc = 0.25f; }
  else if (u < 384) { w = wk;  b = bk;  col = u - 192; dim = 192; }
  else if (u < 576) { w = wv;  b = bv;  col = u - 384; dim = 192; }
  else if (u < 720) { w = wqp; b = bqp; col = u - 576; dim = 144; }
  else if (u < 864) { w = wkp; b = bkp; col = u - 720; dim = 144; }
  else              { w = wvp; b = bvp; col = u - 864; dim = 288; }
  if (kk < 384) Wall[kk * KALL + u] = sc * w[kk * dim + col];
  else          ball[u] = sc * b[col];
}

// ---------------- 2. proj = s @ Wall + ball   [768 x 1152] ----------------
__global__ __launch_bounds__(256) void proj_kernel(const float* s, const float* Wall,
                                                   const float* ball, float* proj) {
  int q0 = blockIdx.x * 32, c0 = blockIdx.y * 64;
  int tid = threadIdx.x;
  int qa = q0 + (tid >> 4) * 2, qb = qa + 1;
  int c = c0 + (tid & 15) * 4;
  const float* sa = s + qa * 384;
  const float* sb = s + qb * 384;
  const float* wp = Wall + c;
  float4 acc0 = {0, 0, 0, 0}, acc1 = {0, 0, 0, 0};
#pragma unroll 4
  for (int k = 0; k < 384; k++) {
    float4 w4 = ld4(wp + k * KALL);
    float a0 = sa[k], a1 = sb[k];
    acc0.x += a0 * w4.x; acc0.y += a0 * w4.y; acc0.z += a0 * w4.z; acc0.w += a0 * w4.w;
    acc1.x += a1 * w4.x; acc1.y += a1 * w4.y; acc1.z += a1 * w4.z; acc1.w += a1 * w4.w;
  }
  float4 b4 = ld4(ball + c);
  acc0.x += b4.x; acc0.y += b4.y; acc0.z += b4.z; acc0.w += b4.w;
  acc1.x += b4.x; acc1.y += b4.y; acc1.z += b4.z; acc1.w += b4.w;
  *(float4*)(proj + (size_t)qa * KALL + c) = acc0;
  *(float4*)(proj + (size_t)qb * KALL + c) = acc1;
}

// ---------------- 3. rigid-transform points + q2/k2 ----------------
__global__ __launch_bounds__(256) void points_kernel(const float* proj, const float* rot,
                                                     const float* trans, float* qpts, float* kpts,
                                                     float* vpts, float* q2, float* k2) {
  int n = blockIdx.x, tid = threadIdx.x;
  __shared__ float sq[12], sk[12];
  if (tid < 12) { sq[tid] = 0.f; sk[tid] = 0.f; }
  __syncthreads();
  if (tid < 192) {
    const float* R = rot + n * 9;
    const float* T = trans + n * 3;
    const float* pr = proj + (size_t)n * KALL;
    int base, P; float* outp; int h; bool isq = false, isk = false;
    if (tid < 48)      { h = tid >> 2; int p = tid & 3; base = 576 + h * 12; P = 4;
                         outp = qpts + n * 144 + h * 12 + p * 3; base += p; isq = true; }
    else if (tid < 96) { int i = tid - 48; h = i >> 2; int p = i & 3; base = 720 + h * 12; P = 4;
                         outp = kpts + n * 144 + h * 12 + p * 3; base += p; isk = true; }
    else               { int i = tid - 96; h = i >> 3; int p = i & 7; base = 864 + h * 24; P = 8;
                         outp = vpts + n * 288 + h * 24 + p * 3; base += p; }
    float l0 = pr[base], l1 = pr[base + P], l2 = pr[base + 2 * P];
    float g0 = R[0] * l0 + R[1] * l1 + R[2] * l2 + T[0];
    float g1 = R[3] * l0 + R[4] * l1 + R[5] * l2 + T[1];
    float g2 = R[6] * l0 + R[7] * l1 + R[8] * l2 + T[2];
    outp[0] = g0; outp[1] = g1; outp[2] = g2;
    float ns = g0 * g0 + g1 * g1 + g2 * g2;
    if (isq) atomicAdd(&sq[h], ns);
    else if (isk) atomicAdd(&sk[h], ns);
  }
  __syncthreads();
  if (tid < 12) { q2[n * 12 + tid] = sq[tid]; k2[n * 12 + tid] = sk[tid]; }
}

// ---------------- 4. fused bias + logits + softmax: one block per q ----------------
// Thread (wave w, lane l) owns rows k = 192w + 64i + l (i=0..2), ALL 12 heads.
// z read row-per-lane (64B-line live set = 12KB/wave, L1-resident); wbt read with
// wave-uniform addresses (scalar-cache path). Logits in registers L[3][12];
// softmax = per-wave butterfly + tiny LDS cross-wave combine. abuf written once.
__global__ __launch_bounds__(256) void attn_kernel(
    const float* z, const float* wbt, const float* bb, const float* proj,
    const float* qpts, const float* kpts, const float* q2, const float* k2,
    const float* mask, const float* hw, float* abuf) {
  int q = blockIdx.x;
  int tid = threadIdx.x;
  int w = tid >> 6, l = tid & 63;
  __shared__ float qws[192], qps[144];
  __shared__ float q2s_[12], bbs_[12], pws_[12];
  __shared__ float mq_s;
  __shared__ float redm[4][12], reds[4][12];

  if (tid < 192) qws[tid] = proj[(size_t)q * KALL + tid];
  if (tid < 144) qps[tid] = qpts[q * 144 + tid];
  if (tid < 12) {
    q2s_[tid] = q2[q * 12 + tid];
    bbs_[tid] = bb[tid];
    float x = hw[tid];
    pws_[tid] = 0.23570226039551584f * (fmaxf(x, 0.f) + log1pf(__expf(-fabsf(x))));
  }
  if (tid == 12) mq_s = mask[q];
  __syncthreads();

  int k0 = 192 * w + l;
  const float* zr = z + ((size_t)q * NN + k0) * 128;

  // --- phase 1: bias accumulation over c (z @ wb), 3 rows x 12 heads ---
  float L[3][12];
#pragma unroll
  for (int i = 0; i < 3; i++)
#pragma unroll
    for (int h = 0; h < 12; h++) L[i][h] = 0.f;
#pragma unroll 2
  for (int c4 = 0; c4 < 128; c4 += 4) {
    float4 z0 = ld4(zr + c4);
    float4 z1 = ld4(zr + 64 * 128 + c4);
    float4 z2 = ld4(zr + 128 * 128 + c4);
#pragma unroll
    for (int h = 0; h < 12; h++) {
      float4 w4 = ld4(wbt + h * 128 + c4);   // wave-uniform address
      L[0][h] += z0.x * w4.x + z0.y * w4.y + z0.z * w4.z + z0.w * w4.w;
      L[1][h] += z1.x * w4.x + z1.y * w4.y + z1.z * w4.z + z1.w * w4.w;
      L[2][h] += z2.x * w4.x + z2.y * w4.y + z2.z * w4.z + z2.w * w4.w;
    }
  }

  // --- phase 2: add qk-dot, point term, mask; scale ---
  float mq = mq_s;
  float mterm[3];
#pragma unroll
  for (int i = 0; i < 3; i++) mterm[i] = INF_ * (mq * mask[k0 + 64 * i] - 1.f);

#pragma unroll
  for (int h = 0; h < 12; h++) {
    float qwh[16], qph[12];
#pragma unroll
    for (int j = 0; j < 16; j++) qwh[j] = qws[h * 16 + j];
#pragma unroll
    for (int j = 0; j < 12; j++) qph[j] = qps[h * 12 + j];
    float q2v = q2s_[h], pwv = pws_[h], bbv = bbs_[h];
#pragma unroll
    for (int i = 0; i < 3; i++) {
      int k = k0 + 64 * i;
      const float* kwp = proj + (size_t)k * KALL + 192 + h * 16;
      float4 a0 = ld4(kwp), a1 = ld4(kwp + 4), a2 = ld4(kwp + 8), a3 = ld4(kwp + 12);
      float dqk = a0.x * qwh[0] + a0.y * qwh[1] + a0.z * qwh[2] + a0.w * qwh[3]
                + a1.x * qwh[4] + a1.y * qwh[5] + a1.z * qwh[6] + a1.w * qwh[7]
                + a2.x * qwh[8] + a2.y * qwh[9] + a2.z * qwh[10] + a2.w * qwh[11]
                + a3.x * qwh[12] + a3.y * qwh[13] + a3.z * qwh[14] + a3.w * qwh[15];
      const float* kpp = kpts + (size_t)k * 144 + h * 12;
      float4 p0 = ld4(kpp), p1 = ld4(kpp + 4), p2 = ld4(kpp + 8);
      float dpt = p0.x * qph[0] + p0.y * qph[1] + p0.z * qph[2] + p0.w * qph[3]
                + p1.x * qph[4] + p1.y * qph[5] + p1.z * qph[6] + p1.w * qph[7]
                + p2.x * qph[8] + p2.y * qph[9] + p2.z * qph[10] + p2.w * qph[11];
      float k2v = k2[k * 12 + h];
      L[i][h] = (L[i][h] + bbv + dqk - 0.5f * pwv * (q2v + k2v - 2.f * dpt) + mterm[i])
                * 0.5773502691896258f;
    }
  }

  // --- phase 3: softmax over k (768) per head ---
  float m[12];
#pragma unroll
  for (int h = 0; h < 12; h++) m[h] = fmaxf(fmaxf(L[0][h], L[1][h]), L[2][h]);
#pragma unroll
  for (int d = 1; d < 64; d <<= 1)
#pragma unroll
    for (int h = 0; h < 12; h++) m[h] = fmaxf(m[h], __shfl_xor(m[h], d, 64));
  if (l == 0)
#pragma unroll
    for (int h = 0; h < 12; h++) redm[w][h] = m[h];
  __syncthreads();
  float M[12];
#pragma unroll
  for (int h = 0; h < 12; h++)
    M[h] = fmaxf(fmaxf(redm[0][h], redm[1][h]), fmaxf(redm[2][h], redm[3][h]));

  float s[12];
#pragma unroll
  for (int h = 0; h < 12; h++) {
    L[0][h] = __expf(L[0][h] - M[h]);
    L[1][h] = __expf(L[1][h] - M[h]);
    L[2][h] = __expf(L[2][h] - M[h]);
    s[h] = L[0][h] + L[1][h] + L[2][h];
  }
#pragma unroll
  for (int d = 1; d < 64; d <<= 1)
#pragma unroll
    for (int h = 0; h < 12; h++) s[h] += __shfl_xor(s[h], d, 64);
  if (l == 0)
#pragma unroll
    for (int h = 0; h < 12; h++) reds[w][h] = s[h];
  __syncthreads();
#pragma unroll
  for (int h = 0; h < 12; h++) {
    float inv = 1.f / (reds[0][h] + reds[1][h] + reds[2][h] + reds[3][h]);
    float* ap = abuf + ((size_t)q * 12 + h) * NN + k0;
    ap[0] = L[0][h] * inv;
    ap[64] = L[1][h] * inv;
    ap[128] = L[2][h] * inv;
  }
}

// ---------------- 5. o_pair[q][h][c] = sum_k a[q,h,k] z[q,k,c]  -> cat cols 576.. ----------------
// block per q; wave w owns heads {3w,3w+1,3w+2} (wave-uniform -> a_s reads are broadcasts);
// lane owns c-pair; z read coalesced b64; 3 ds_read_b128 per 4k per wave.
__global__ __launch_bounds__(256) void opair_kernel(const float* z, const float* abuf, float* cat) {
  int q = blockIdx.x, tid = threadIdx.x;
  __shared__ float a_s[9216];    // [h][k]
  for (int i = tid; i < 9216; i += 256) a_s[i] = abuf[(size_t)q * 9216 + i];
  __syncthreads();
  int cp = tid & 63, w = tid >> 6;
  int h0 = w * 3;
  const float* zb = z + (size_t)q * NN * 128 + 2 * cp;
  float acc[3][2] = {{0, 0}, {0, 0}, {0, 0}};
#pragma unroll 2
  for (int k4 = 0; k4 < NN; k4 += 4) {
    float4 a0 = *(const float4*)&a_s[(h0 + 0) * NN + k4];
    float4 a1 = *(const float4*)&a_s[(h0 + 1) * NN + k4];
    float4 a2 = *(const float4*)&a_s[(h0 + 2) * NN + k4];
    float2 z0 = *(const float2*)(zb + (size_t)(k4 + 0) * 128);
    float2 z1 = *(const float2*)(zb + (size_t)(k4 + 1) * 128);
    float2 z2 = *(const float2*)(zb + (size_t)(k4 + 2) * 128);
    float2 z3 = *(const float2*)(zb + (size_t)(k4 + 3) * 128);
    acc[0][0] += a0.x * z0.x + a0.y * z1.x + a0.z * z2.x + a0.w * z3.x;
    acc[0][1] += a0.x * z0.y + a0.y * z1.y + a0.z * z2.y + a0.w * z3.y;
    acc[1][0] += a1.x * z0.x + a1.y * z1.x + a1.z * z2.x + a1.w * z3.x;
    acc[1][1] += a1.x * z0.y + a1.y * z1.y + a1.z * z2.y + a1.w * z3.y;
    acc[2][0] += a2.x * z0.x + a2.y * z1.x + a2.z * z2.x + a2.w * z3.x;
    acc[2][1] += a2.x * z0.y + a2.y * z1.y + a2.z * z2.y + a2.w * z3.y;
  }
#pragma unroll
  for (int j = 0; j < 3; j++) {
    float2 o = {acc[j][0], acc[j][1]};
    *(float2*)(cat + (size_t)q * CATD + 576 + (h0 + j) * 128 + 2 * cp) = o;
  }
}

// ---------------- 6. o + o_pt (inverse rigid + norm) -> cat cols 0..576 ----------------
__global__ __launch_bounds__(256) void ov_kernel(const float* proj, const float* vpts,
                                                 const float* abuf, const float* rot,
                                                 const float* trans, float* cat) {
  int h = blockIdx.x, q0 = blockIdx.y * 24;
  int tid = threadIdx.x;
  __shared__ float opt[24][24];
  if (tid < 240) {
    int ql = tid / 10, g = tid - ql * 10;
    int q = q0 + ql;
    const float* ap = abuf + ((size_t)q * 12 + h) * NN;
    const float* vb;
    int stride;
    if (g < 4) { vb = proj + 384 + h * 16 + g * 4; stride = KALL; }
    else       { vb = vpts + h * 24 + (g - 4) * 4; stride = 288;  }
    float4 acc = {0, 0, 0, 0};
#pragma unroll 4
    for (int k = 0; k < NN; k++) {
      float av = ap[k];
      float4 v4 = ld4(vb + (size_t)k * stride);
      acc.x += av * v4.x; acc.y += av * v4.y; acc.z += av * v4.z; acc.w += av * v4.w;
    }
    if (g < 4) {
      *(float4*)(cat + (size_t)q * CATD + h * 16 + g * 4) = acc;
    } else {
      *(float4*)(&opt[ql][(g - 4) * 4]) = acc;
    }
  }
  __syncthreads();
  if (tid < 192) {
    int ql = tid >> 3, p = tid & 7;
    int q = q0 + ql;
    float gx = opt[ql][p * 3], gy = opt[ql][p * 3 + 1], gz = opt[ql][p * 3 + 2];
    const float* R = rot + q * 9;
    const float* T = trans + q * 3;
    float dx = gx - T[0], dy = gy - T[1], dz = gz - T[2];
    float lx = R[0] * dx + R[3] * dy + R[6] * dz;  // R^T
    float ly = R[1] * dx + R[4] * dy + R[7] * dz;
    float lz = R[2] * dx + R[5] * dy + R[8] * dz;
    float nrm = sqrtf(lx * lx + ly * ly + lz * lz + 1e-8f);
    int hp = h * 8 + p;
    float* co = cat + (size_t)q * CATD;
    co[192 + hp] = lx; co[288 + hp] = ly; co[384 + hp] = lz; co[480 + hp] = nrm;
  }
}

// ---------------- 7a. out partials: split-K GEMM  cat[768x2112] @ wo[2112x384] ----------------
__global__ __launch_bounds__(256) void out_part_kernel(const float* cat, const float* wo,
                                                       float* part) {
  int q0 = blockIdx.x * 16, c0 = blockIdx.y * 64, k0 = blockIdx.z * 264;
  int tid = threadIdx.x;
  int q = q0 + (tid >> 4);
  int c = c0 + (tid & 15) * 4;
  const float* cp = cat + (size_t)q * CATD + k0;
  const float* wp = wo + (size_t)k0 * 384 + c;
  float4 acc = {0, 0, 0, 0};
#pragma unroll 8
  for (int k = 0; k < 264; k++) {
    float a = cp[k];
    float4 w4 = ld4(wp + (size_t)k * 384);
    acc.x += a * w4.x; acc.y += a * w4.y; acc.z += a * w4.z; acc.w += a * w4.w;
  }
  *(float4*)(part + ((size_t)blockIdx.z * 768 + q) * 384 + c) = acc;
}

// ---------------- 7b. out = sum_j part[j] + b_o ----------------
__global__ __launch_bounds__(256) void out_reduce_kernel(const float* part, const float* bo,
                                                         float* out) {
  int idx = blockIdx.x * 256 + threadIdx.x;
  int q = idx / 96, cg = idx - q * 96;
  int c = cg * 4;
  float4 acc = ld4(bo + c);
#pragma unroll
  for (int j = 0; j < 8; j++) {
    float4 p = ld4(part + ((size_t)j * 768 + q) * 384 + c);
    acc.x += p.x; acc.y += p.y; acc.z += p.z; acc.w += p.w;
  }
  *(float4*)(out + (size_t)q * 384 + c) = acc;
}

extern "C" void kernel_launch(void* const* d_in, const int* in_sizes, int n_in,
                              void* d_out, int out_size, void* d_ws, size_t ws_size,
                              hipStream_t stream) {
  const float* s     = (const float*)d_in[0];
  const float* z     = (const float*)d_in[1];
  const float* rot   = (const float*)d_in[2];
  const float* trans = (const float*)d_in[3];
  const float* mask  = (const float*)d_in[4];
  const float* wq    = (const float*)d_in[5];
  const float* bq    = (const float*)d_in[6];
  const float* wk    = (const float*)d_in[7];
  const float* bk    = (const float*)d_in[8];
  const float* wv    = (const float*)d_in[9];
  const float* bv    = (const float*)d_in[10];
  const float* wqp   = (const float*)d_in[11];
  const float* bqp   = (const float*)d_in[12];
  const float* wkp   = (const float*)d_in[13];
  const float* bkp   = (const float*)d_in[14];
  const float* wvp   = (const float*)d_in[15];
  const float* bvp   = (const float*)d_in[16];
  const float* wb    = (const float*)d_in[17];
  const float* bb    = (const float*)d_in[18];
  const float* hw    = (const float*)d_in[19];
  const float* wo    = (const float*)d_in[20];
  const float* bo    = (const float*)d_in[21];
  float* out = (float*)d_out;

  float* ws = (float*)d_ws;
  float* proj  = ws;                       // 768*1152
  float* Wall  = proj + 884736;            // 384*1152
  float* ball  = Wall + 442368;            // 1152
  float* qpts  = ball + 1152;              // 768*144
  float* kpts  = qpts + 110592;            // 768*144
  float* vpts  = kpts + 110592;            // 768*288
  float* q2    = vpts + 221184;            // 768*12
  float* k2    = q2 + 9216;                // 768*12
  float* abuf  = k2 + 9216;                // 768*12*768
  float* cat   = abuf + 7077888;           // 768*2112
  float* part  = cat + 1622016;            // 8*768*384
  float* wbt   = part + 2359296;           // 12*128

  pack_kernel<<<dim3((385 * KALL + 255) / 256), 256, 0, stream>>>(
      wq, bq, wk, bk, wv, bv, wqp, bqp, wkp, bkp, wvp, bvp, wb, Wall, ball, wbt);
  proj_kernel<<<dim3(24, 18), 256, 0, stream>>>(s, Wall, ball, proj);
  points_kernel<<<dim3(768), 256, 0, stream>>>(proj, rot, trans, qpts, kpts, vpts, q2, k2);
  attn_kernel<<<dim3(768), 256, 0, stream>>>(z, wbt, bb, proj, qpts, kpts, q2, k2, mask, hw, abuf);
  opair_kernel<<<dim3(768), 256, 0, stream>>>(z, abuf, cat);
  ov_kernel<<<dim3(12, 32), 256, 0, stream>>>(proj, vpts, abuf, rot, trans, cat);
  out_part_kernel<<<dim3(48, 6, 8), 256, 0, stream>>>(cat, wo, part);
  out_reduce_kernel<<<dim3(288), 256, 0, stream>>>(part, bo, out);
}